// Round 1
// baseline (697.019 us; speedup 1.0000x reference)
//
#include <hip/hip_runtime.h>

#define NN 50000
#define EE 800000
#define ET 850000   // EE + NN self loops
#define HH 4
#define CC 64
#define FDIM 256    // HH*CC

#define SCAN_BLK 512
#define SCAN_NB ((NN + SCAN_BLK - 1) / SCAN_BLK)   // 98

typedef unsigned short ushort;
typedef __bf16 bf16x8 __attribute__((ext_vector_type(8)));
typedef float floatx4 __attribute__((ext_vector_type(4)));
typedef ushort ushort8v __attribute__((ext_vector_type(8)));
struct ushort4s { ushort x, y, z, w; };

__device__ __forceinline__ ushort f2bf(float f) {
  union { float f; unsigned u; } v; v.f = f;
  unsigned r = v.u + 0x7fffu + ((v.u >> 16) & 1u);  // RNE
  return (ushort)(r >> 16);
}
__device__ __forceinline__ float bf2f(ushort u) {
  return __uint_as_float(((unsigned)u) << 16);
}

// ---------- edge-index dtype handling (int32 vs int64 at runtime) ----------
__device__ __forceinline__ int get_edge(const void* p, int is64, long long idx) {
  if (is64) return (int)((const long long*)p)[idx];
  return ((const int*)p)[idx];
}

__global__ void detect_kernel(const unsigned int* p, int* flag) {
  // int64 with values < 50000 => every odd 32-bit word is 0
  __shared__ unsigned red[256];
  int t = threadIdx.x;
  unsigned o = 0;
  for (int i = 0; i < 4; i++) o |= p[(t * 4 + i) * 2 + 1];
  red[t] = o;
  __syncthreads();
  for (int s = 128; s > 0; s >>= 1) {
    if (t < s) red[t] |= red[t + s];
    __syncthreads();
  }
  if (t == 0) *flag = (red[0] == 0) ? 1 : 0;
}

// ---------- CSR build over dst ----------
__global__ void degree_kernel(const void* eidx, const int* flag, int* deg) {
  int k = blockIdx.x * blockDim.x + threadIdx.x;
  if (k >= ET) return;
  int is64 = *flag;
  int dst = (k < EE) ? get_edge(eidx, is64, (long long)EE + k) : (k - EE);
  atomicAdd(&deg[dst], 1);
}

__global__ __launch_bounds__(SCAN_BLK) void scan1_kernel(const int* __restrict__ deg,
                                                         int* __restrict__ rowptr,
                                                         int* __restrict__ bsum) {
  __shared__ int sm[SCAN_BLK];
  int t = threadIdx.x;
  int i = blockIdx.x * SCAN_BLK + t;
  int v = (i < NN) ? deg[i] : 0;
  sm[t] = v;
  __syncthreads();
#pragma unroll
  for (int o = 1; o < SCAN_BLK; o <<= 1) {
    int u = (t >= o) ? sm[t - o] : 0;
    __syncthreads();
    sm[t] += u;
    __syncthreads();
  }
  if (i < NN) rowptr[i] = sm[t] - v;                 // local exclusive
  if (t == SCAN_BLK - 1) bsum[blockIdx.x] = sm[t];   // block total
}

__global__ __launch_bounds__(128) void scan2_kernel(const int* __restrict__ bsum,
                                                    int* __restrict__ boff,
                                                    int* __restrict__ rowptr) {
  __shared__ int sm[128];
  int t = threadIdx.x;
  int v = (t < SCAN_NB) ? bsum[t] : 0;
  sm[t] = v;
  __syncthreads();
#pragma unroll
  for (int o = 1; o < 128; o <<= 1) {
    int u = (t >= o) ? sm[t - o] : 0;
    __syncthreads();
    sm[t] += u;
    __syncthreads();
  }
  if (t < SCAN_NB) boff[t] = sm[t] - v;  // exclusive block offset
  if (t == 0) rowptr[NN] = ET;
}

__global__ __launch_bounds__(SCAN_BLK) void scan3_kernel(int* __restrict__ rowptr,
                                                         int* __restrict__ cursor,
                                                         const int* __restrict__ boff) {
  int i = blockIdx.x * SCAN_BLK + threadIdx.x;
  if (i >= NN) return;
  int v = rowptr[i] + boff[blockIdx.x];
  rowptr[i] = v;
  cursor[i] = v;
}

__global__ void fill_kernel(const void* eidx, const int* flag, int* cursor, int* csr_src) {
  int k = blockIdx.x * blockDim.x + threadIdx.x;
  if (k >= ET) return;
  int is64 = *flag;
  int src, dst;
  if (k < EE) {
    src = get_edge(eidx, is64, k);
    dst = get_edge(eidx, is64, (long long)EE + k);
  } else {
    src = dst = k - EE;
  }
  int pos = atomicAdd(&cursor[dst], 1);
  csr_src[pos] = src;
}

// all three weight transposes in one dispatch (grid.y selects the matrix)
__global__ void conv_w_kernel(const float* __restrict__ W0, const float* __restrict__ W1,
                              const float* __restrict__ W2,
                              ushort* __restrict__ T0, ushort* __restrict__ T1,
                              ushort* __restrict__ T2) {
  const float* W = (blockIdx.y == 0) ? W0 : (blockIdx.y == 1) ? W1 : W2;
  ushort* Wt = (blockIdx.y == 0) ? T0 : (blockIdx.y == 1) ? T1 : T2;
  int idx = blockIdx.x * 256 + threadIdx.x;  // 65536
  int k = idx >> 8, n = idx & 255;
  Wt[n * 256 + k] = f2bf(W[idx]);  // transpose: Wt[n][k]
}

// ---------- bf16 MFMA GEMM: small-tile + LDS (6 blocks/CU) + s/d epilogue ----------
// C[M,256] = A[M,256] @ B[256,256] (B given transposed).
// Block = 64 rows x 128 cols, 4 waves, wave tile 32x64 (2x4 16x16 subtiles).
// 1564 blocks = 6.1 blocks/CU: co-resident blocks' MFMA hides each other's
// barrier drains (R8 LDS @3 blocks/CU had MfmaUtil ~4%; R10 small-tile w/o LDS
// falsified occupancy-alone — this is the untried small-tile+LDS cell).
// LDS 12KB: wave w stages A sub-tile w (16 rows) and B sub-tiles 2w,2w+1.
// MODE 0: A f32 (layer 0), inline cvt. MODE 1: A bf16 agg output, GraphNorm+
// LeakyReLU fused into staging from prev layer's colsum/colsumsq stats.
// Epilogue: wave w covers cols bcol0+(w&1)*64..+64 = one complete head ->
// plain stores of s,d.
template <int MODE>
__global__ __launch_bounds__(256) void gemm_bf16(const void* __restrict__ Ap,
                                                 const ushort* __restrict__ Bt,
                                                 ushort* __restrict__ C,
                                                 const float* __restrict__ as_,
                                                 const float* __restrict__ ad_,
                                                 float* __restrict__ s_arr,
                                                 float* __restrict__ d_arr,
                                                 const float* __restrict__ colsum,
                                                 const float* __restrict__ colsumsq,
                                                 const float* __restrict__ ga,
                                                 const float* __restrict__ gw,
                                                 const float* __restrict__ gb) {
  __shared__ ushort As[4 * 512];
  __shared__ ushort Bs[8 * 512];
  __shared__ float scs[FDIM], shs[FDIM];
  int tid = threadIdx.x, w = tid >> 6, l = tid & 63;
  int brow0 = blockIdx.x * 64, bcol0 = blockIdx.y * 128;
  int lm = l & 15, lk = (l >> 4) * 8;
  // staging addresses: wave w -> A sub-tile w, B sub-tiles 2w, 2w+1
  int arA = min(brow0 + w * 16 + lm, NN - 1);
  size_t arowA = (size_t)arA * 256 + lk;
  const ushort* bg0 = Bt + (size_t)(bcol0 + (2 * w) * 16 + lm) * 256 + lk;
  const ushort* bg1 = Bt + (size_t)(bcol0 + (2 * w + 1) * 16 + lm) * 256 + lk;

  if constexpr (MODE == 1) {
    const float invn = 1.0f / (float)NN;
    float mu = colsum[tid] * invn;
    float ex2 = colsumsq[tid] * invn;
    float a = ga[tid];
    float var = fmaxf(ex2 - (2.f * a - a * a) * mu * mu, 0.f);
    float s = gw[tid] * rsqrtf(var + 1e-5f);
    scs[tid] = s;
    shs[tid] = gb[tid] - s * a * mu;
    __syncthreads();
  }

  floatx4 acc[2][4];
#pragma unroll
  for (int i = 0; i < 2; i++)
#pragma unroll
    for (int j = 0; j < 4; j++) acc[i][j] = floatx4{0.f, 0.f, 0.f, 0.f};

  int wm = (w >> 1) * 2, wn = (w & 1) * 4;   // wave: row sub-tiles wm..wm+1, col sub-tiles wn..wn+3

  for (int k0 = 0; k0 < 256; k0 += 32) {
    ushort8v a0;
    if constexpr (MODE == 0) {
      const float* p0 = (const float*)Ap + arowA + k0;
      float4 u0 = *(const float4*)p0, v0 = *(const float4*)(p0 + 4);
      a0 = ushort8v{f2bf(u0.x), f2bf(u0.y), f2bf(u0.z), f2bf(u0.w),
                    f2bf(v0.x), f2bf(v0.y), f2bf(v0.z), f2bf(v0.w)};
    } else {
      ushort8v r0 = *(const ushort8v*)((const ushort*)Ap + arowA + k0);
      int kb = k0 + lk;
#pragma unroll
      for (int j = 0; j < 8; j++) {
        float sc = scs[kb + j], sh = shs[kb + j];
        float y0 = fmaf(sc, bf2f(r0[j]), sh);
        y0 = fmaxf(y0, 0.01f * y0);   // LeakyReLU(0.01)
        a0[j] = f2bf(y0);
      }
    }
    ushort8v b0 = *(const ushort8v*)(bg0 + k0);
    ushort8v b1 = *(const ushort8v*)(bg1 + k0);
    *(ushort8v*)&As[w * 512 + l * 8] = a0;
    *(ushort8v*)&Bs[(2 * w) * 512 + l * 8] = b0;
    *(ushort8v*)&Bs[(2 * w + 1) * 512 + l * 8] = b1;
    __syncthreads();
    bf16x8 af[2], bfr[4];
#pragma unroll
    for (int i = 0; i < 2; i++) af[i] = *(const bf16x8*)&As[(wm + i) * 512 + l * 8];
#pragma unroll
    for (int j = 0; j < 4; j++) bfr[j] = *(const bf16x8*)&Bs[(wn + j) * 512 + l * 8];
#pragma unroll
    for (int i = 0; i < 2; i++)
#pragma unroll
      for (int j = 0; j < 4; j++)
        acc[i][j] = __builtin_amdgcn_mfma_f32_16x16x32_bf16(af[i], bfr[j], acc[i][j], 0, 0, 0);
    __syncthreads();
  }

  int quad = l >> 4;
  // ----- C store -----
#pragma unroll
  for (int i = 0; i < 2; i++) {
    int r0 = brow0 + (wm + i) * 16 + quad * 4;
#pragma unroll
    for (int j = 0; j < 4; j++) {
      int col = bcol0 + (wn + j) * 16 + lm;
#pragma unroll
      for (int r = 0; r < 4; r++) {
        int row = r0 + r;
        if (row < NN) C[(size_t)row * 256 + col] = f2bf(acc[i][j][r]);
      }
    }
  }
  // ----- s/d epilogue: this wave owns head (bcol0>>6)+(w&1) for its rows -----
  float asv[4], adv[4];
#pragma unroll
  for (int j = 0; j < 4; j++) {
    int col = bcol0 + (wn + j) * 16 + lm;
    asv[j] = as_[col];
    adv[j] = ad_[col];
  }
  int head = (bcol0 >> 6) + (w & 1);
#pragma unroll
  for (int i = 0; i < 2; i++) {
#pragma unroll
    for (int r = 0; r < 4; r++) {
      float sp = acc[i][0][r] * asv[0] + acc[i][1][r] * asv[1] +
                 acc[i][2][r] * asv[2] + acc[i][3][r] * asv[3];
      float dp = acc[i][0][r] * adv[0] + acc[i][1][r] * adv[1] +
                 acc[i][2][r] * adv[2] + acc[i][3][r] * adv[3];
      sp += __shfl_xor(sp, 1); dp += __shfl_xor(dp, 1);
      sp += __shfl_xor(sp, 2); dp += __shfl_xor(dp, 2);
      sp += __shfl_xor(sp, 4); dp += __shfl_xor(dp, 4);
      sp += __shfl_xor(sp, 8); dp += __shfl_xor(dp, 8);
      if (lm == 0) {
        int row = brow0 + (wm + i) * 16 + quad * 4 + r;
        if (row < NN) {
          s_arr[row * HH + head] = sp;   // plain store: unique (row,head) per wave
          d_arr[row * HH + head] = dp;
        }
      }
    }
  }
}

// ---------- aggregation: one wave per node; 2 edges concurrent per wave ----------
// R-new: 32 lanes x 16B (dwordx4) cover one 512B row; the two wave-halves take
// alternating 4-edge groups. Halves per-lane VMEM instr count and the redundant
// per-edge softmax/addr VALU (each half only computes e/exp for its own edges);
// FMA total unchanged. Cross-half combine: shfl_xor(32) on den + 8 accumulators.
// Theory: agg was issue/latency-bound (VALUBusy 47%, hbm 47%, occ 69%), not BW.
template <bool CONCAT>
__global__ __launch_bounds__(256) void agg_kernel(const ushort* __restrict__ hb,
                                                  const float* __restrict__ s_arr,
                                                  const float* __restrict__ d_arr,
                                                  const int* __restrict__ rowptr,
                                                  const int* __restrict__ csr_src,
                                                  const float* __restrict__ bias,
                                                  void* __restrict__ outp) {
  int w = __builtin_amdgcn_readfirstlane(threadIdx.x >> 6);
  int l = threadIdx.x & 63;
  int half = l >> 5;        // which edge-parity group this lane handles
  int ll = l & 31;          // channel-lane: bytes ll*16..+16 of row = channels 8ll..8ll+7
  int head = ll >> 3;       // (8*ll)>>6
  int n = blockIdx.x * 4 + w;
  int beg = rowptr[n], end = rowptr[n + 1];
  float dh = d_arr[n * HH + head];
  float a[8];
#pragma unroll
  for (int j = 0; j < 8; j++) a[j] = 0.f;
  float den = 0.f;

  int cnt = end - beg;
  int main_end = beg + (cnt & ~7);

  for (int b0 = beg; b0 < main_end; b0 += 8) {
    int i0 = b0 + half * 4;
    int s0 = csr_src[i0], s1 = csr_src[i0 + 1], s2 = csr_src[i0 + 2], s3 = csr_src[i0 + 3];
    float e0 = s_arr[s0 * HH + head] + dh;
    float e1 = s_arr[s1 * HH + head] + dh;
    float e2 = s_arr[s2 * HH + head] + dh;
    float e3 = s_arr[s3 * HH + head] + dh;
    ushort8v h0 = *(const ushort8v*)(hb + (unsigned)(s0 * FDIM) + ll * 8);
    ushort8v h1 = *(const ushort8v*)(hb + (unsigned)(s1 * FDIM) + ll * 8);
    ushort8v h2 = *(const ushort8v*)(hb + (unsigned)(s2 * FDIM) + ll * 8);
    ushort8v h3 = *(const ushort8v*)(hb + (unsigned)(s3 * FDIM) + ll * 8);
    e0 = (e0 > 0.f) ? e0 : 0.2f * e0;  float w0 = __expf(e0);
    e1 = (e1 > 0.f) ? e1 : 0.2f * e1;  float w1 = __expf(e1);
    e2 = (e2 > 0.f) ? e2 : 0.2f * e2;  float w2 = __expf(e2);
    e3 = (e3 > 0.f) ? e3 : 0.2f * e3;  float w3 = __expf(e3);
    den += (w0 + w1) + (w2 + w3);
#pragma unroll
    for (int j = 0; j < 8; j++) {
      a[j] = fmaf(w0, bf2f(h0[j]), a[j]);
      a[j] = fmaf(w1, bf2f(h1[j]), a[j]);
      a[j] = fmaf(w2, bf2f(h2[j]), a[j]);
      a[j] = fmaf(w3, bf2f(h3[j]), a[j]);
    }
  }
  // masked tail: up to 7 edges; half0 covers tail slots 0..3, half1 slots 4..7
  if (main_end < end) {
    int i0 = main_end + half * 4;
#pragma unroll
    for (int t = 0; t < 4; t++) {
      int idx = i0 + t;
      int sid = csr_src[(idx < end) ? idx : (end - 1)];
      float e0 = s_arr[sid * HH + head] + dh;
      ushort8v h0 = *(const ushort8v*)(hb + (unsigned)(sid * FDIM) + ll * 8);
      e0 = (e0 > 0.f) ? e0 : 0.2f * e0;
      float w0 = (idx < end) ? __expf(e0) : 0.f;
      den += w0;
#pragma unroll
      for (int j = 0; j < 8; j++) a[j] = fmaf(w0, bf2f(h0[j]), a[j]);
    }
  }

  // combine the two edge-parity halves (same head per xor-32 pair)
  den += __shfl_xor(den, 32);
  float inv = 1.0f / den;  // self loop guarantees den > 0
#pragma unroll
  for (int j = 0; j < 8; j++) {
    a[j] += __shfl_xor(a[j], 32);
    a[j] *= inv;           // per-head normalization BEFORE any head reduce
  }

  if (CONCAT) {
    if (half == 0) {
      float4 bv0 = ((const float4*)bias)[ll * 2];
      float4 bv1 = ((const float4*)bias)[ll * 2 + 1];
      ushort8v o;
      o[0] = f2bf(a[0] + bv0.x); o[1] = f2bf(a[1] + bv0.y);
      o[2] = f2bf(a[2] + bv0.z); o[3] = f2bf(a[3] + bv0.w);
      o[4] = f2bf(a[4] + bv1.x); o[5] = f2bf(a[5] + bv1.y);
      o[6] = f2bf(a[6] + bv1.z); o[7] = f2bf(a[7] + bv1.w);
      *(ushort8v*)((ushort*)outp + (size_t)n * FDIM + ll * 8) = o;
    }
  } else {
    // mean over heads: partners ll^8, ll^16 (same within-head channel)
#pragma unroll
    for (int j = 0; j < 8; j++) {
      a[j] += __shfl_xor(a[j], 8);
      a[j] += __shfl_xor(a[j], 16);
    }
    if (l < 8) {
      const float4* bp = (const float4*)bias;
      float4 b0 = bp[l * 2], b1 = bp[l * 2 + 1];
      float4 o0{0.25f * a[0] + b0.x, 0.25f * a[1] + b0.y,
                0.25f * a[2] + b0.z, 0.25f * a[3] + b0.w};
      float4 o1{0.25f * a[4] + b1.x, 0.25f * a[5] + b1.y,
                0.25f * a[6] + b1.z, 0.25f * a[7] + b1.w};
      ((float4*)outp)[(size_t)n * 16 + l * 2] = o0;
      ((float4*)outp)[(size_t)n * 16 + l * 2 + 1] = o1;
    }
  }
}

// ---------- GraphNorm reduce ----------
__global__ __launch_bounds__(256) void norm_reduce_bf(const ushort* __restrict__ xin,
                                                      float* colsum, float* colsumsq) {
  __shared__ float4 sm1[256], sm2[256];
  int t = threadIdx.x;
  int c4 = (t & 63) * 4;
  int rl = t >> 6;
  int r0 = blockIdx.x * 128;
  int r1 = min(NN, r0 + 128);
  float s0 = 0.f, s1 = 0.f, s2 = 0.f, s3 = 0.f;
  float q0 = 0.f, q1 = 0.f, q2 = 0.f, q3 = 0.f;
  for (int r = r0 + rl; r < r1; r += 4) {
    ushort4s v = *(const ushort4s*)(xin + (size_t)r * FDIM + c4);
    float f0 = bf2f(v.x), f1 = bf2f(v.y), f2 = bf2f(v.z), f3 = bf2f(v.w);
    s0 += f0; q0 += f0 * f0;
    s1 += f1; q1 += f1 * f1;
    s2 += f2; q2 += f2 * f2;
    s3 += f3; q3 += f3 * f3;
  }
  sm1[t] = float4{s0, s1, s2, s3};
  sm2[t] = float4{q0, q1, q2, q3};
  __syncthreads();
  if (t < 64) {
    float4 a = sm1[t], b = sm1[t + 64], c = sm1[t + 128], d = sm1[t + 192];
    atomicAdd(&colsum[c4 + 0], a.x + b.x + c.x + d.x);
    atomicAdd(&colsum[c4 + 1], a.y + b.y + c.y + d.y);
    atomicAdd(&colsum[c4 + 2], a.z + b.z + c.z + d.z);
    atomicAdd(&colsum[c4 + 3], a.w + b.w + c.w + d.w);
    float4 e = sm2[t], f = sm2[t + 64], g = sm2[t + 128], h = sm2[t + 192];
    atomicAdd(&colsumsq[c4 + 0], e.x + f.x + g.x + h.x);
    atomicAdd(&colsumsq[c4 + 1], e.y + f.y + g.y + h.y);
    atomicAdd(&colsumsq[c4 + 2], e.z + f.z + g.z + h.z);
    atomicAdd(&colsumsq[c4 + 3], e.w + f.w + g.w + h.w);
  }
}

__global__ __launch_bounds__(256) void norm_reduce_f32(const float* __restrict__ xin,
                                                       float* colsum, float* colsumsq) {
  int f = threadIdx.x & (CC - 1);
  int rl = threadIdx.x / CC;
  int r0 = blockIdx.x * 128;
  int r1 = min(NN, r0 + 128);
  float s1 = 0.f, s2 = 0.f;
  for (int r = r0 + rl; r < r1; r += 4) {
    float v = xin[(size_t)r * CC + f];
    s1 += v; s2 += v * v;
  }
  atomicAdd(&colsum[f], s1);
  atomicAdd(&colsumsq[f], s2);
}

// ---------- MLP 64->32->16->2 with fused GraphNorm+LeakyReLU on input ----------
__global__ __launch_bounds__(256) void mlp_kernel(const float* __restrict__ xin,
                                                  const float* __restrict__ colsum,
                                                  const float* __restrict__ colsumsq,
                                                  const float* __restrict__ ga,
                                                  const float* __restrict__ gw,
                                                  const float* __restrict__ gb,
                                                  const float* mW0, const float* mb0,
                                                  const float* mW1, const float* mb1,
                                                  const float* mW2, const float* mb2,
                                                  float* __restrict__ out) {
  __shared__ float W0s[64 * 32];
  __shared__ float W1s[32 * 16];
  __shared__ float W2s[16 * 2];
  __shared__ float b0s[32], b1s[16], b2s[2];
  __shared__ float sc[CC], sh[CC];
  int t = threadIdx.x;
  for (int i = t; i < 2048; i += 256) W0s[i] = mW0[i];
  for (int i = t; i < 512; i += 256) W1s[i] = mW1[i];
  if (t < 32) { W2s[t] = mW2[t]; b0s[t] = mb0[t]; }
  if (t < 16) b1s[t] = mb1[t];
  if (t < 2) b2s[t] = mb2[t];
  if (t < CC) {
    const float invn = 1.0f / (float)NN;
    float mu = colsum[t] * invn;
    float ex2 = colsumsq[t] * invn;
    float a = ga[t];
    float var = fmaxf(ex2 - (2.f * a - a * a) * mu * mu, 0.f);
    float s = gw[t] * rsqrtf(var + 1e-5f);
    sc[t] = s; sh[t] = gb[t] - s * a * mu;
  }
  __syncthreads();
  int node = blockIdx.x * 256 + t;
  if (node >= NN) return;
  float in[64];
  const float* xr = xin + (size_t)node * 64;
#pragma unroll
  for (int k = 0; k < 64; k++) {
    float y = sc[k] * xr[k] + sh[k];
    in[k] = (y > 0.f) ? y : 0.01f * y;   // GraphNorm + LeakyReLU(0.01) fused
  }
  float h1[32];
#pragma unroll
  for (int j = 0; j < 32; j++) h1[j] = b0s[j];
#pragma unroll
  for (int k = 0; k < 64; k++) {
    float v = in[k];
#pragma unroll
    for (int j = 0; j < 32; j++) h1[j] += v * W0s[k * 32 + j];
  }
#pragma unroll
  for (int j = 0; j < 32; j++) h1[j] = fmaxf(h1[j], 0.f);
  float h2[16];
#pragma unroll
  for (int j = 0; j < 16; j++) h2[j] = b1s[j];
#pragma unroll
  for (int k = 0; k < 32; k++) {
    float v = h1[k];
#pragma unroll
    for (int j = 0; j < 16; j++) h2[j] += v * W1s[k * 16 + j];
  }
#pragma unroll
  for (int j = 0; j < 16; j++) h2[j] = fmaxf(h2[j], 0.f);
  float o0 = b2s[0], o1 = b2s[1];
#pragma unroll
  for (int k = 0; k < 16; k++) {
    o0 += h2[k] * W2s[k * 2 + 0];
    o1 += h2[k] * W2s[k * 2 + 1];
  }
  out[(size_t)node * 2 + 0] = o0;
  out[(size_t)node * 2 + 1] = o1;
}

extern "C" void kernel_launch(void* const* d_in, const int* in_sizes, int n_in,
                              void* d_out, int out_size, void* d_ws, size_t ws_size,
                              hipStream_t stream) {
  const float* x = (const float*)d_in[0];
  const void* ei = d_in[1];
  const float* W[3]   = {(const float*)d_in[2],  (const float*)d_in[9],  (const float*)d_in[16]};
  const float* as_[3] = {(const float*)d_in[3],  (const float*)d_in[10], (const float*)d_in[17]};
  const float* ad_[3] = {(const float*)d_in[4],  (const float*)d_in[11], (const float*)d_in[18]};
  const float* b_[3]  = {(const float*)d_in[5],  (const float*)d_in[12], (const float*)d_in[19]};
  const float* gw[3]  = {(const float*)d_in[6],  (const float*)d_in[13], (const float*)d_in[20]};
  const float* gb[3]  = {(const float*)d_in[7],  (const float*)d_in[14], (const float*)d_in[21]};
  const float* ga[3]  = {(const float*)d_in[8],  (const float*)d_in[15], (const float*)d_in[22]};
  const float* mW0 = (const float*)d_in[23];
  const float* mb0 = (const float*)d_in[24];
  const float* mW1 = (const float*)d_in[25];
  const float* mb1 = (const float*)d_in[26];
  const float* mW2 = (const float*)d_in[27];
  const float* mb2 = (const float*)d_in[28];
  float* out = (float*)d_out;

  char* ws = (char*)d_ws;
  size_t off = 0;
  auto take = [&](size_t bytes) -> char* {
    char* p = ws + off;
    off = (off + bytes + 255) & ~(size_t)255;
    return p;
  };
  ushort* hb    = (ushort*)take((size_t)NN * FDIM * 2);
  ushort* aggb  = (ushort*)take((size_t)NN * FDIM * 2);
  float* bufD   = (float*)take((size_t)NN * CC * 4);
  ushort* Wt[3];
  for (int i = 0; i < 3; i++) Wt[i] = (ushort*)take((size_t)256 * 256 * 2);
  float* s_arr  = (float*)take((size_t)NN * HH * 4);
  float* d_arr  = (float*)take((size_t)NN * HH * 4);
  // zero-region: deg + 3 per-layer stat buffers (colsum|colsumsq each) -> ONE memset
  char* zbase   = (char*)take(0);
  int* deg      = (int*)take((size_t)NN * 4);
  float* cs[3];
  for (int i = 0; i < 3; i++) cs[i] = (float*)take(2048);   // [0:256)=colsum, [256:512)=colsumsq
  size_t zlen   = (size_t)(((char*)cs[2] + 2048) - zbase);
  int* cursor   = (int*)take((size_t)NN * 4);
  int* rowptr   = (int*)take((size_t)(NN + 1) * 4);
  int* csr_src  = (int*)take((size_t)ET * 4);
  int* bsum     = (int*)take(512);
  int* boff     = (int*)take(512);
  int* flag     = (int*)take(256);

  hipMemsetAsync(zbase, 0, zlen, stream);   // deg + all 3 layers' norm stats

  // CSR build (reused by all 3 layers)
  detect_kernel<<<1, 256, 0, stream>>>((const unsigned int*)ei, flag);
  degree_kernel<<<(ET + 255) / 256, 256, 0, stream>>>(ei, flag, deg);
  scan1_kernel<<<SCAN_NB, SCAN_BLK, 0, stream>>>(deg, rowptr, bsum);
  scan2_kernel<<<1, 128, 0, stream>>>(bsum, boff, rowptr);
  scan3_kernel<<<SCAN_NB, SCAN_BLK, 0, stream>>>(rowptr, cursor, boff);
  fill_kernel<<<(ET + 255) / 256, 256, 0, stream>>>(ei, flag, cursor, csr_src);

  // weight prep (x is consumed in f32 directly by layer-0 gemm)
  conv_w_kernel<<<dim3(256, 3), 256, 0, stream>>>(W[0], W[1], W[2], Wt[0], Wt[1], Wt[2]);

  dim3 ggrid((NN + 63) / 64, 2);
  for (int L = 0; L < 3; L++) {
    if (L == 0)
      gemm_bf16<0><<<ggrid, 256, 0, stream>>>((const void*)x, Wt[0], hb,
                                              as_[0], ad_[0], s_arr, d_arr,
                                              nullptr, nullptr, nullptr, nullptr, nullptr);
    else
      gemm_bf16<1><<<ggrid, 256, 0, stream>>>((const void*)aggb, Wt[L], hb,
                                              as_[L], ad_[L], s_arr, d_arr,
                                              cs[L - 1], cs[L - 1] + 256,
                                              ga[L - 1], gw[L - 1], gb[L - 1]);
    if (L < 2) {
      agg_kernel<true><<<NN / 4, 256, 0, stream>>>(hb, s_arr, d_arr, rowptr, csr_src, b_[L], aggb);
      norm_reduce_bf<<<(NN + 127) / 128, 256, 0, stream>>>(aggb, cs[L], cs[L] + 256);
    } else {
      agg_kernel<false><<<NN / 4, 256, 0, stream>>>(hb, s_arr, d_arr, rowptr, csr_src, b_[L], bufD);
      norm_reduce_f32<<<(NN + 127) / 128, 256, 0, stream>>>(bufD, cs[2], cs[2] + 256);
    }
  }
  mlp_kernel<<<(NN + 255) / 256, 256, 0, stream>>>(bufD, cs[2], cs[2] + 256,
                                                   ga[2], gw[2], gb[2],
                                                   mW0, mb0, mW1, mb1, mW2, mb2, out);
}

// Round 2
// 686.162 us; speedup vs baseline: 1.0158x; 1.0158x over previous
//
#include <hip/hip_runtime.h>

#define NN 50000
#define EE 800000
#define ET 850000   // EE + NN self loops
#define HH 4
#define CC 64
#define FDIM 256    // HH*CC

#define SCAN_BLK 512
#define SCAN_NB ((NN + SCAN_BLK - 1) / SCAN_BLK)   // 98

typedef unsigned short ushort;
typedef __bf16 bf16x8 __attribute__((ext_vector_type(8)));
typedef float floatx4 __attribute__((ext_vector_type(4)));
typedef ushort ushort8v __attribute__((ext_vector_type(8)));
struct ushort4s { ushort x, y, z, w; };

__device__ __forceinline__ ushort f2bf(float f) {
  union { float f; unsigned u; } v; v.f = f;
  unsigned r = v.u + 0x7fffu + ((v.u >> 16) & 1u);  // RNE
  return (ushort)(r >> 16);
}
__device__ __forceinline__ float bf2f(ushort u) {
  return __uint_as_float(((unsigned)u) << 16);
}

// ---------- edge-index dtype handling (int32 vs int64 at runtime) ----------
__device__ __forceinline__ int get_edge(const void* p, int is64, long long idx) {
  if (is64) return (int)((const long long*)p)[idx];
  return ((const int*)p)[idx];
}

__global__ void detect_kernel(const unsigned int* p, int* flag) {
  // int64 with values < 50000 => every odd 32-bit word is 0
  __shared__ unsigned red[256];
  int t = threadIdx.x;
  unsigned o = 0;
  for (int i = 0; i < 4; i++) o |= p[(t * 4 + i) * 2 + 1];
  red[t] = o;
  __syncthreads();
  for (int s = 128; s > 0; s >>= 1) {
    if (t < s) red[t] |= red[t + s];
    __syncthreads();
  }
  if (t == 0) *flag = (red[0] == 0) ? 1 : 0;
}

// ---------- CSR build over dst ----------
__global__ void degree_kernel(const void* eidx, const int* flag, int* deg) {
  int k = blockIdx.x * blockDim.x + threadIdx.x;
  if (k >= ET) return;
  int is64 = *flag;
  int dst = (k < EE) ? get_edge(eidx, is64, (long long)EE + k) : (k - EE);
  atomicAdd(&deg[dst], 1);
}

__global__ __launch_bounds__(SCAN_BLK) void scan1_kernel(const int* __restrict__ deg,
                                                         int* __restrict__ rowptr,
                                                         int* __restrict__ bsum) {
  __shared__ int sm[SCAN_BLK];
  int t = threadIdx.x;
  int i = blockIdx.x * SCAN_BLK + t;
  int v = (i < NN) ? deg[i] : 0;
  sm[t] = v;
  __syncthreads();
#pragma unroll
  for (int o = 1; o < SCAN_BLK; o <<= 1) {
    int u = (t >= o) ? sm[t - o] : 0;
    __syncthreads();
    sm[t] += u;
    __syncthreads();
  }
  if (i < NN) rowptr[i] = sm[t] - v;                 // local exclusive
  if (t == SCAN_BLK - 1) bsum[blockIdx.x] = sm[t];   // block total
}

__global__ __launch_bounds__(128) void scan2_kernel(const int* __restrict__ bsum,
                                                    int* __restrict__ boff,
                                                    int* __restrict__ rowptr) {
  __shared__ int sm[128];
  int t = threadIdx.x;
  int v = (t < SCAN_NB) ? bsum[t] : 0;
  sm[t] = v;
  __syncthreads();
#pragma unroll
  for (int o = 1; o < 128; o <<= 1) {
    int u = (t >= o) ? sm[t - o] : 0;
    __syncthreads();
    sm[t] += u;
    __syncthreads();
  }
  if (t < SCAN_NB) boff[t] = sm[t] - v;  // exclusive block offset
  if (t == 0) rowptr[NN] = ET;
}

__global__ __launch_bounds__(SCAN_BLK) void scan3_kernel(int* __restrict__ rowptr,
                                                         int* __restrict__ cursor,
                                                         const int* __restrict__ boff) {
  int i = blockIdx.x * SCAN_BLK + threadIdx.x;
  if (i >= NN) return;
  int v = rowptr[i] + boff[blockIdx.x];
  rowptr[i] = v;
  cursor[i] = v;
}

__global__ void fill_kernel(const void* eidx, const int* flag, int* cursor, int* csr_src) {
  int k = blockIdx.x * blockDim.x + threadIdx.x;
  if (k >= ET) return;
  int is64 = *flag;
  int src, dst;
  if (k < EE) {
    src = get_edge(eidx, is64, k);
    dst = get_edge(eidx, is64, (long long)EE + k);
  } else {
    src = dst = k - EE;
  }
  int pos = atomicAdd(&cursor[dst], 1);
  csr_src[pos] = src;
}

// all three weight transposes in one dispatch (grid.y selects the matrix)
__global__ void conv_w_kernel(const float* __restrict__ W0, const float* __restrict__ W1,
                              const float* __restrict__ W2,
                              ushort* __restrict__ T0, ushort* __restrict__ T1,
                              ushort* __restrict__ T2) {
  const float* W = (blockIdx.y == 0) ? W0 : (blockIdx.y == 1) ? W1 : W2;
  ushort* Wt = (blockIdx.y == 0) ? T0 : (blockIdx.y == 1) ? T1 : T2;
  int idx = blockIdx.x * 256 + threadIdx.x;  // 65536
  int k = idx >> 8, n = idx & 255;
  Wt[n * 256 + k] = f2bf(W[idx]);  // transpose: Wt[n][k]
}

// ---------- bf16 MFMA GEMM: small-tile + LDS (6 blocks/CU) + s/d epilogue ----------
// C[M,256] = A[M,256] @ B[256,256] (B given transposed).
// Block = 64 rows x 128 cols, 4 waves, wave tile 32x64 (2x4 16x16 subtiles).
// 1564 blocks = 6.1 blocks/CU: co-resident blocks' MFMA hides each other's
// barrier drains (R8 LDS @3 blocks/CU had MfmaUtil ~4%; R10 small-tile w/o LDS
// falsified occupancy-alone — this is the untried small-tile+LDS cell).
// LDS 12KB: wave w stages A sub-tile w (16 rows) and B sub-tiles 2w,2w+1.
// MODE 0: A f32 (layer 0), inline cvt. MODE 1: A bf16 agg output, GraphNorm+
// LeakyReLU fused into staging from prev layer's colsum/colsumsq stats.
// Epilogue: wave w covers cols bcol0+(w&1)*64..+64 = one complete head ->
// plain stores of s,d.
template <int MODE>
__global__ __launch_bounds__(256) void gemm_bf16(const void* __restrict__ Ap,
                                                 const ushort* __restrict__ Bt,
                                                 ushort* __restrict__ C,
                                                 const float* __restrict__ as_,
                                                 const float* __restrict__ ad_,
                                                 float* __restrict__ s_arr,
                                                 float* __restrict__ d_arr,
                                                 const float* __restrict__ colsum,
                                                 const float* __restrict__ colsumsq,
                                                 const float* __restrict__ ga,
                                                 const float* __restrict__ gw,
                                                 const float* __restrict__ gb) {
  __shared__ ushort As[4 * 512];
  __shared__ ushort Bs[8 * 512];
  __shared__ float scs[FDIM], shs[FDIM];
  int tid = threadIdx.x, w = tid >> 6, l = tid & 63;
  int brow0 = blockIdx.x * 64, bcol0 = blockIdx.y * 128;
  int lm = l & 15, lk = (l >> 4) * 8;
  // staging addresses: wave w -> A sub-tile w, B sub-tiles 2w, 2w+1
  int arA = min(brow0 + w * 16 + lm, NN - 1);
  size_t arowA = (size_t)arA * 256 + lk;
  const ushort* bg0 = Bt + (size_t)(bcol0 + (2 * w) * 16 + lm) * 256 + lk;
  const ushort* bg1 = Bt + (size_t)(bcol0 + (2 * w + 1) * 16 + lm) * 256 + lk;

  if constexpr (MODE == 1) {
    const float invn = 1.0f / (float)NN;
    float mu = colsum[tid] * invn;
    float ex2 = colsumsq[tid] * invn;
    float a = ga[tid];
    float var = fmaxf(ex2 - (2.f * a - a * a) * mu * mu, 0.f);
    float s = gw[tid] * rsqrtf(var + 1e-5f);
    scs[tid] = s;
    shs[tid] = gb[tid] - s * a * mu;
    __syncthreads();
  }

  floatx4 acc[2][4];
#pragma unroll
  for (int i = 0; i < 2; i++)
#pragma unroll
    for (int j = 0; j < 4; j++) acc[i][j] = floatx4{0.f, 0.f, 0.f, 0.f};

  int wm = (w >> 1) * 2, wn = (w & 1) * 4;   // wave: row sub-tiles wm..wm+1, col sub-tiles wn..wn+3

  for (int k0 = 0; k0 < 256; k0 += 32) {
    ushort8v a0;
    if constexpr (MODE == 0) {
      const float* p0 = (const float*)Ap + arowA + k0;
      float4 u0 = *(const float4*)p0, v0 = *(const float4*)(p0 + 4);
      a0 = ushort8v{f2bf(u0.x), f2bf(u0.y), f2bf(u0.z), f2bf(u0.w),
                    f2bf(v0.x), f2bf(v0.y), f2bf(v0.z), f2bf(v0.w)};
    } else {
      ushort8v r0 = *(const ushort8v*)((const ushort*)Ap + arowA + k0);
      int kb = k0 + lk;
#pragma unroll
      for (int j = 0; j < 8; j++) {
        float sc = scs[kb + j], sh = shs[kb + j];
        float y0 = fmaf(sc, bf2f(r0[j]), sh);
        y0 = fmaxf(y0, 0.01f * y0);   // LeakyReLU(0.01)
        a0[j] = f2bf(y0);
      }
    }
    ushort8v b0 = *(const ushort8v*)(bg0 + k0);
    ushort8v b1 = *(const ushort8v*)(bg1 + k0);
    *(ushort8v*)&As[w * 512 + l * 8] = a0;
    *(ushort8v*)&Bs[(2 * w) * 512 + l * 8] = b0;
    *(ushort8v*)&Bs[(2 * w + 1) * 512 + l * 8] = b1;
    __syncthreads();
    bf16x8 af[2], bfr[4];
#pragma unroll
    for (int i = 0; i < 2; i++) af[i] = *(const bf16x8*)&As[(wm + i) * 512 + l * 8];
#pragma unroll
    for (int j = 0; j < 4; j++) bfr[j] = *(const bf16x8*)&Bs[(wn + j) * 512 + l * 8];
#pragma unroll
    for (int i = 0; i < 2; i++)
#pragma unroll
      for (int j = 0; j < 4; j++)
        acc[i][j] = __builtin_amdgcn_mfma_f32_16x16x32_bf16(af[i], bfr[j], acc[i][j], 0, 0, 0);
    __syncthreads();
  }

  int quad = l >> 4;
  // ----- C store -----
#pragma unroll
  for (int i = 0; i < 2; i++) {
    int r0 = brow0 + (wm + i) * 16 + quad * 4;
#pragma unroll
    for (int j = 0; j < 4; j++) {
      int col = bcol0 + (wn + j) * 16 + lm;
#pragma unroll
      for (int r = 0; r < 4; r++) {
        int row = r0 + r;
        if (row < NN) C[(size_t)row * 256 + col] = f2bf(acc[i][j][r]);
      }
    }
  }
  // ----- s/d epilogue: this wave owns head (bcol0>>6)+(w&1) for its rows -----
  float asv[4], adv[4];
#pragma unroll
  for (int j = 0; j < 4; j++) {
    int col = bcol0 + (wn + j) * 16 + lm;
    asv[j] = as_[col];
    adv[j] = ad_[col];
  }
  int head = (bcol0 >> 6) + (w & 1);
#pragma unroll
  for (int i = 0; i < 2; i++) {
#pragma unroll
    for (int r = 0; r < 4; r++) {
      float sp = acc[i][0][r] * asv[0] + acc[i][1][r] * asv[1] +
                 acc[i][2][r] * asv[2] + acc[i][3][r] * asv[3];
      float dp = acc[i][0][r] * adv[0] + acc[i][1][r] * adv[1] +
                 acc[i][2][r] * adv[2] + acc[i][3][r] * adv[3];
      sp += __shfl_xor(sp, 1); dp += __shfl_xor(dp, 1);
      sp += __shfl_xor(sp, 2); dp += __shfl_xor(dp, 2);
      sp += __shfl_xor(sp, 4); dp += __shfl_xor(dp, 4);
      sp += __shfl_xor(sp, 8); dp += __shfl_xor(dp, 8);
      if (lm == 0) {
        int row = brow0 + (wm + i) * 16 + quad * 4 + r;
        if (row < NN) {
          s_arr[row * HH + head] = sp;   // plain store: unique (row,head) per wave
          d_arr[row * HH + head] = dp;
        }
      }
    }
  }
}

// ---------- aggregation: one wave per node, all heads; fused edge softmax ----------
// R2: R0 layout (64 lanes x 8B per edge) restored — R1's 2-edge split REDUCED
// in-flight gathers and got 5% slower (memory-side bound, not issue-bound).
// Main loop deepened to 16 edges: 16 csr + 16 s-loads + 16 h-gathers all issued
// before any consume -> 2x outstanding misses per wave. Tail tiers 8/4/1 keep
// low-degree nodes from serializing. Discriminates arrival-limited (faster) vs
// L2-miss-path service-limited (flat => agg at structural floor ~205MB/8XCD).
template <bool CONCAT>
__global__ __launch_bounds__(256) void agg_kernel(const ushort* __restrict__ hb,
                                                  const float* __restrict__ s_arr,
                                                  const float* __restrict__ d_arr,
                                                  const int* __restrict__ rowptr,
                                                  const int* __restrict__ csr_src,
                                                  const float* __restrict__ bias,
                                                  void* __restrict__ outp) {
  int w = __builtin_amdgcn_readfirstlane(threadIdx.x >> 6);
  int l = threadIdx.x & 63;
  int head = l >> 4;
  int n = blockIdx.x * 4 + w;
  int beg = rowptr[n], end = rowptr[n + 1];
  float dh = d_arr[n * HH + head];
  float a0 = 0.f, a1 = 0.f, a2 = 0.f, a3 = 0.f, den = 0.f;

  int i = beg;
  // ---- 16-deep main: all loads issued before any consume (max MLP) ----
  for (; i + 16 <= end; i += 16) {
    int ss[16];
#pragma unroll
    for (int t = 0; t < 16; t++) ss[t] = csr_src[i + t];
    float ee[16];
#pragma unroll
    for (int t = 0; t < 16; t++) ee[t] = s_arr[ss[t] * HH + head];
    ushort4s hh[16];
#pragma unroll
    for (int t = 0; t < 16; t++)
      hh[t] = *(const ushort4s*)(hb + (unsigned)(ss[t] * FDIM + l * 4));
#pragma unroll
    for (int t = 0; t < 16; t++) {
      float e = ee[t] + dh;
      e = (e > 0.f) ? e : 0.2f * e;
      float wt = __expf(e);
      den += wt;
      a0 = fmaf(wt, bf2f(hh[t].x), a0);
      a1 = fmaf(wt, bf2f(hh[t].y), a1);
      a2 = fmaf(wt, bf2f(hh[t].z), a2);
      a3 = fmaf(wt, bf2f(hh[t].w), a3);
    }
  }
  // ---- 8-tier ----
  for (; i + 8 <= end; i += 8) {
    int ss[8];
#pragma unroll
    for (int t = 0; t < 8; t++) ss[t] = csr_src[i + t];
    float ee[8];
#pragma unroll
    for (int t = 0; t < 8; t++) ee[t] = s_arr[ss[t] * HH + head];
    ushort4s hh[8];
#pragma unroll
    for (int t = 0; t < 8; t++)
      hh[t] = *(const ushort4s*)(hb + (unsigned)(ss[t] * FDIM + l * 4));
#pragma unroll
    for (int t = 0; t < 8; t++) {
      float e = ee[t] + dh;
      e = (e > 0.f) ? e : 0.2f * e;
      float wt = __expf(e);
      den += wt;
      a0 = fmaf(wt, bf2f(hh[t].x), a0);
      a1 = fmaf(wt, bf2f(hh[t].y), a1);
      a2 = fmaf(wt, bf2f(hh[t].z), a2);
      a3 = fmaf(wt, bf2f(hh[t].w), a3);
    }
  }
  // ---- 4-tier ----
  for (; i + 4 <= end; i += 4) {
    int ss[4];
#pragma unroll
    for (int t = 0; t < 4; t++) ss[t] = csr_src[i + t];
    float ee[4];
#pragma unroll
    for (int t = 0; t < 4; t++) ee[t] = s_arr[ss[t] * HH + head];
    ushort4s hh[4];
#pragma unroll
    for (int t = 0; t < 4; t++)
      hh[t] = *(const ushort4s*)(hb + (unsigned)(ss[t] * FDIM + l * 4));
#pragma unroll
    for (int t = 0; t < 4; t++) {
      float e = ee[t] + dh;
      e = (e > 0.f) ? e : 0.2f * e;
      float wt = __expf(e);
      den += wt;
      a0 = fmaf(wt, bf2f(hh[t].x), a0);
      a1 = fmaf(wt, bf2f(hh[t].y), a1);
      a2 = fmaf(wt, bf2f(hh[t].z), a2);
      a3 = fmaf(wt, bf2f(hh[t].w), a3);
    }
  }
  // ---- scalar tail ----
  for (; i < end; i++) {
    int s0 = csr_src[i];
    float e0 = s_arr[s0 * HH + head] + dh;
    ushort4s h0 = *(const ushort4s*)(hb + (unsigned)(s0 * FDIM + l * 4));
    e0 = (e0 > 0.f) ? e0 : 0.2f * e0;
    float w0 = __expf(e0);
    den += w0;
    a0 = fmaf(w0, bf2f(h0.x), a0); a1 = fmaf(w0, bf2f(h0.y), a1);
    a2 = fmaf(w0, bf2f(h0.z), a2); a3 = fmaf(w0, bf2f(h0.w), a3);
  }
  float inv = 1.0f / den;  // self loop guarantees den > 0
  float r0 = a0 * inv, r1 = a1 * inv, r2 = a2 * inv, r3 = a3 * inv;

  if (CONCAT) {
    float4 bv = ((const float4*)bias)[l];
    ushort4s o;
    o.x = f2bf(r0 + bv.x); o.y = f2bf(r1 + bv.y);
    o.z = f2bf(r2 + bv.z); o.w = f2bf(r3 + bv.w);
    ((ushort4s*)outp)[(unsigned)(n * 64 + l)] = o;
  } else {
    r0 += __shfl_xor(r0, 16); r1 += __shfl_xor(r1, 16);
    r2 += __shfl_xor(r2, 16); r3 += __shfl_xor(r3, 16);
    r0 += __shfl_xor(r0, 32); r1 += __shfl_xor(r1, 32);
    r2 += __shfl_xor(r2, 32); r3 += __shfl_xor(r3, 32);
    if (l < 16) {
      float4 bv = ((const float4*)bias)[l];
      float4 o;
      o.x = 0.25f * r0 + bv.x; o.y = 0.25f * r1 + bv.y;
      o.z = 0.25f * r2 + bv.z; o.w = 0.25f * r3 + bv.w;
      ((float4*)outp)[(unsigned)(n * 16 + l)] = o;
    }
  }
}

// ---------- GraphNorm reduce ----------
__global__ __launch_bounds__(256) void norm_reduce_bf(const ushort* __restrict__ xin,
                                                      float* colsum, float* colsumsq) {
  __shared__ float4 sm1[256], sm2[256];
  int t = threadIdx.x;
  int c4 = (t & 63) * 4;
  int rl = t >> 6;
  int r0 = blockIdx.x * 128;
  int r1 = min(NN, r0 + 128);
  float s0 = 0.f, s1 = 0.f, s2 = 0.f, s3 = 0.f;
  float q0 = 0.f, q1 = 0.f, q2 = 0.f, q3 = 0.f;
  for (int r = r0 + rl; r < r1; r += 4) {
    ushort4s v = *(const ushort4s*)(xin + (size_t)r * FDIM + c4);
    float f0 = bf2f(v.x), f1 = bf2f(v.y), f2 = bf2f(v.z), f3 = bf2f(v.w);
    s0 += f0; q0 += f0 * f0;
    s1 += f1; q1 += f1 * f1;
    s2 += f2; q2 += f2 * f2;
    s3 += f3; q3 += f3 * f3;
  }
  sm1[t] = float4{s0, s1, s2, s3};
  sm2[t] = float4{q0, q1, q2, q3};
  __syncthreads();
  if (t < 64) {
    float4 a = sm1[t], b = sm1[t + 64], c = sm1[t + 128], d = sm1[t + 192];
    atomicAdd(&colsum[c4 + 0], a.x + b.x + c.x + d.x);
    atomicAdd(&colsum[c4 + 1], a.y + b.y + c.y + d.y);
    atomicAdd(&colsum[c4 + 2], a.z + b.z + c.z + d.z);
    atomicAdd(&colsum[c4 + 3], a.w + b.w + c.w + d.w);
    float4 e = sm2[t], f = sm2[t + 64], g = sm2[t + 128], h = sm2[t + 192];
    atomicAdd(&colsumsq[c4 + 0], e.x + f.x + g.x + h.x);
    atomicAdd(&colsumsq[c4 + 1], e.y + f.y + g.y + h.y);
    atomicAdd(&colsumsq[c4 + 2], e.z + f.z + g.z + h.z);
    atomicAdd(&colsumsq[c4 + 3], e.w + f.w + g.w + h.w);
  }
}

__global__ __launch_bounds__(256) void norm_reduce_f32(const float* __restrict__ xin,
                                                       float* colsum, float* colsumsq) {
  int f = threadIdx.x & (CC - 1);
  int rl = threadIdx.x / CC;
  int r0 = blockIdx.x * 128;
  int r1 = min(NN, r0 + 128);
  float s1 = 0.f, s2 = 0.f;
  for (int r = r0 + rl; r < r1; r += 4) {
    float v = xin[(size_t)r * CC + f];
    s1 += v; s2 += v * v;
  }
  atomicAdd(&colsum[f], s1);
  atomicAdd(&colsumsq[f], s2);
}

// ---------- MLP 64->32->16->2 with fused GraphNorm+LeakyReLU on input ----------
__global__ __launch_bounds__(256) void mlp_kernel(const float* __restrict__ xin,
                                                  const float* __restrict__ colsum,
                                                  const float* __restrict__ colsumsq,
                                                  const float* __restrict__ ga,
                                                  const float* __restrict__ gw,
                                                  const float* __restrict__ gb,
                                                  const float* mW0, const float* mb0,
                                                  const float* mW1, const float* mb1,
                                                  const float* mW2, const float* mb2,
                                                  float* __restrict__ out) {
  __shared__ float W0s[64 * 32];
  __shared__ float W1s[32 * 16];
  __shared__ float W2s[16 * 2];
  __shared__ float b0s[32], b1s[16], b2s[2];
  __shared__ float sc[CC], sh[CC];
  int t = threadIdx.x;
  for (int i = t; i < 2048; i += 256) W0s[i] = mW0[i];
  for (int i = t; i < 512; i += 256) W1s[i] = mW1[i];
  if (t < 32) { W2s[t] = mW2[t]; b0s[t] = mb0[t]; }
  if (t < 16) b1s[t] = mb1[t];
  if (t < 2) b2s[t] = mb2[t];
  if (t < CC) {
    const float invn = 1.0f / (float)NN;
    float mu = colsum[t] * invn;
    float ex2 = colsumsq[t] * invn;
    float a = ga[t];
    float var = fmaxf(ex2 - (2.f * a - a * a) * mu * mu, 0.f);
    float s = gw[t] * rsqrtf(var + 1e-5f);
    sc[t] = s; sh[t] = gb[t] - s * a * mu;
  }
  __syncthreads();
  int node = blockIdx.x * 256 + t;
  if (node >= NN) return;
  float in[64];
  const float* xr = xin + (size_t)node * 64;
#pragma unroll
  for (int k = 0; k < 64; k++) {
    float y = sc[k] * xr[k] + sh[k];
    in[k] = (y > 0.f) ? y : 0.01f * y;   // GraphNorm + LeakyReLU(0.01) fused
  }
  float h1[32];
#pragma unroll
  for (int j = 0; j < 32; j++) h1[j] = b0s[j];
#pragma unroll
  for (int k = 0; k < 64; k++) {
    float v = in[k];
#pragma unroll
    for (int j = 0; j < 32; j++) h1[j] += v * W0s[k * 32 + j];
  }
#pragma unroll
  for (int j = 0; j < 32; j++) h1[j] = fmaxf(h1[j], 0.f);
  float h2[16];
#pragma unroll
  for (int j = 0; j < 16; j++) h2[j] = b1s[j];
#pragma unroll
  for (int k = 0; k < 32; k++) {
    float v = h1[k];
#pragma unroll
    for (int j = 0; j < 16; j++) h2[j] += v * W1s[k * 16 + j];
  }
#pragma unroll
  for (int j = 0; j < 16; j++) h2[j] = fmaxf(h2[j], 0.f);
  float o0 = b2s[0], o1 = b2s[1];
#pragma unroll
  for (int k = 0; k < 16; k++) {
    o0 += h2[k] * W2s[k * 2 + 0];
    o1 += h2[k] * W2s[k * 2 + 1];
  }
  out[(size_t)node * 2 + 0] = o0;
  out[(size_t)node * 2 + 1] = o1;
}

extern "C" void kernel_launch(void* const* d_in, const int* in_sizes, int n_in,
                              void* d_out, int out_size, void* d_ws, size_t ws_size,
                              hipStream_t stream) {
  const float* x = (const float*)d_in[0];
  const void* ei = d_in[1];
  const float* W[3]   = {(const float*)d_in[2],  (const float*)d_in[9],  (const float*)d_in[16]};
  const float* as_[3] = {(const float*)d_in[3],  (const float*)d_in[10], (const float*)d_in[17]};
  const float* ad_[3] = {(const float*)d_in[4],  (const float*)d_in[11], (const float*)d_in[18]};
  const float* b_[3]  = {(const float*)d_in[5],  (const float*)d_in[12], (const float*)d_in[19]};
  const float* gw[3]  = {(const float*)d_in[6],  (const float*)d_in[13], (const float*)d_in[20]};
  const float* gb[3]  = {(const float*)d_in[7],  (const float*)d_in[14], (const float*)d_in[21]};
  const float* ga[3]  = {(const float*)d_in[8],  (const float*)d_in[15], (const float*)d_in[22]};
  const float* mW0 = (const float*)d_in[23];
  const float* mb0 = (const float*)d_in[24];
  const float* mW1 = (const float*)d_in[25];
  const float* mb1 = (const float*)d_in[26];
  const float* mW2 = (const float*)d_in[27];
  const float* mb2 = (const float*)d_in[28];
  float* out = (float*)d_out;

  char* ws = (char*)d_ws;
  size_t off = 0;
  auto take = [&](size_t bytes) -> char* {
    char* p = ws + off;
    off = (off + bytes + 255) & ~(size_t)255;
    return p;
  };
  ushort* hb    = (ushort*)take((size_t)NN * FDIM * 2);
  ushort* aggb  = (ushort*)take((size_t)NN * FDIM * 2);
  float* bufD   = (float*)take((size_t)NN * CC * 4);
  ushort* Wt[3];
  for (int i = 0; i < 3; i++) Wt[i] = (ushort*)take((size_t)256 * 256 * 2);
  float* s_arr  = (float*)take((size_t)NN * HH * 4);
  float* d_arr  = (float*)take((size_t)NN * HH * 4);
  // zero-region: deg + 3 per-layer stat buffers (colsum|colsumsq each) -> ONE memset
  char* zbase   = (char*)take(0);
  int* deg      = (int*)take((size_t)NN * 4);
  float* cs[3];
  for (int i = 0; i < 3; i++) cs[i] = (float*)take(2048);   // [0:256)=colsum, [256:512)=colsumsq
  size_t zlen   = (size_t)(((char*)cs[2] + 2048) - zbase);
  int* cursor   = (int*)take((size_t)NN * 4);
  int* rowptr   = (int*)take((size_t)(NN + 1) * 4);
  int* csr_src  = (int*)take((size_t)ET * 4);
  int* bsum     = (int*)take(512);
  int* boff     = (int*)take(512);
  int* flag     = (int*)take(256);

  hipMemsetAsync(zbase, 0, zlen, stream);   // deg + all 3 layers' norm stats

  // CSR build (reused by all 3 layers)
  detect_kernel<<<1, 256, 0, stream>>>((const unsigned int*)ei, flag);
  degree_kernel<<<(ET + 255) / 256, 256, 0, stream>>>(ei, flag, deg);
  scan1_kernel<<<SCAN_NB, SCAN_BLK, 0, stream>>>(deg, rowptr, bsum);
  scan2_kernel<<<1, 128, 0, stream>>>(bsum, boff, rowptr);
  scan3_kernel<<<SCAN_NB, SCAN_BLK, 0, stream>>>(rowptr, cursor, boff);
  fill_kernel<<<(ET + 255) / 256, 256, 0, stream>>>(ei, flag, cursor, csr_src);

  // weight prep (x is consumed in f32 directly by layer-0 gemm)
  conv_w_kernel<<<dim3(256, 3), 256, 0, stream>>>(W[0], W[1], W[2], Wt[0], Wt[1], Wt[2]);

  dim3 ggrid((NN + 63) / 64, 2);
  for (int L = 0; L < 3; L++) {
    if (L == 0)
      gemm_bf16<0><<<ggrid, 256, 0, stream>>>((const void*)x, Wt[0], hb,
                                              as_[0], ad_[0], s_arr, d_arr,
                                              nullptr, nullptr, nullptr, nullptr, nullptr);
    else
      gemm_bf16<1><<<ggrid, 256, 0, stream>>>((const void*)aggb, Wt[L], hb,
                                              as_[L], ad_[L], s_arr, d_arr,
                                              cs[L - 1], cs[L - 1] + 256,
                                              ga[L - 1], gw[L - 1], gb[L - 1]);
    if (L < 2) {
      agg_kernel<true><<<NN / 4, 256, 0, stream>>>(hb, s_arr, d_arr, rowptr, csr_src, b_[L], aggb);
      norm_reduce_bf<<<(NN + 127) / 128, 256, 0, stream>>>(aggb, cs[L], cs[L] + 256);
    } else {
      agg_kernel<false><<<NN / 4, 256, 0, stream>>>(hb, s_arr, d_arr, rowptr, csr_src, b_[L], bufD);
      norm_reduce_f32<<<(NN + 127) / 128, 256, 0, stream>>>(bufD, cs[2], cs[2] + 256);
    }
  }
  mlp_kernel<<<(NN + 255) / 256, 256, 0, stream>>>(bufD, cs[2], cs[2] + 256,
                                                   ga[2], gw[2], gb[2],
                                                   mW0, mb0, mW1, mb1, mW2, mb2, out);
}